// Round 8
// baseline (139.610 us; speedup 1.0000x reference)
//
#include <hip/hip_runtime.h>
#include <hip/hip_bf16.h>

typedef __attribute__((ext_vector_type(4))) float f32x4;
typedef __attribute__((ext_vector_type(8))) short s16x8;
typedef __attribute__((ext_vector_type(8))) unsigned short u16x8;

#define DEVFN static __device__ __forceinline__

DEVFN unsigned short f2bf(float f) {
  union { float f; unsigned int u; } v; v.f = f;
  unsigned int u = v.u;
  u += 0x7fffu + ((u >> 16) & 1u);   // RNE
  return (unsigned short)(u >> 16);
}

DEVFN unsigned int cvt_pk(float a, float b) {
  __hip_bfloat162 h = __float22bfloat162_rn(make_float2(a, b));
  union { __hip_bfloat162 h; unsigned int u; } v; v.h = h; return v.u;
}

DEVFN void gl_lds16(const void* g, void* l) {
  __builtin_amdgcn_global_load_lds((__attribute__((address_space(1))) void*)g,
                                   (__attribute__((address_space(3))) void*)l, 16, 0, 0);
}

// ws layout
#define DG_OFF 0
#define DB_OFF 2048
#define UG_OFF 4096
#define UB_OFF 12288
#define W1_BYTE 81920        // [32 kc][128 R][64 kp] bf16 swizzled; (R,kp)=(n>>1,(n&1)*32+k)
#define W2_BYTE 606208       // [8 nt][4 kc][128 n][64 k] bf16 swizzled

// ---------- merged prep ----------
__global__ void prep_kernel(const float* __restrict__ cond,
                            const float* __restrict__ dgm, const float* __restrict__ dbt,
                            const float* __restrict__ ugm, const float* __restrict__ ubt,
                            const float* __restrict__ Wd, const float* __restrict__ Wu,
                            char* __restrict__ ws) {
  __shared__ float lc[4096];
  __shared__ float red[2048];
  const int t = threadIdx.x;

  if (blockIdx.x < 32) {
    // W1 image: chunk kc2 = [128 R][64 kp], elem (R,kp) = Wd[kc2*32 + (kp&31)][2R + (kp>>5)]
    const int kc2 = blockIdx.x;
    const int R = t >> 1, h = t & 1;
    const float* sp = Wd + (size_t)(kc2 * 32) * 256 + 2 * R + h;
    unsigned short tmp[32];
#pragma unroll
    for (int kk = 0; kk < 32; ++kk) tmp[kk] = f2bf(sp[(size_t)kk * 256]);
    char* dst = ws + W1_BYTE + (size_t)kc2 * 16384 + R * 128;
#pragma unroll
    for (int gi = 0; gi < 4; ++gi) {
      u16x8 v;
#pragma unroll
      for (int e = 0; e < 8; ++e) v[e] = tmp[gi * 8 + e];
      int G = h * 4 + gi;
      *(u16x8*)(dst + ((G ^ (R & 7)) << 4)) = v;
    }
    return;
  }
  if (blockIdx.x < 64) {
    // W2 image (unchanged): [8 nt][4 kc][128 n][64 k]
    int b2 = blockIdx.x - 32;
    int ntile = b2 >> 2, kc = b2 & 3;
    const int n = t >> 1, kh = t & 1;
    const float* sp = Wu + (size_t)(kc * 64 + kh * 32) * 1024 + ntile * 128 + n;
    unsigned short tmp[32];
#pragma unroll
    for (int kk = 0; kk < 32; ++kk) tmp[kk] = f2bf(sp[(size_t)kk * 1024]);
    char* dst = ws + W2_BYTE + (size_t)(ntile * 4 + kc) * 16384 + n * 128;
#pragma unroll
    for (int gi = 0; gi < 4; ++gi) {
      u16x8 v;
#pragma unroll
      for (int e = 0; e < 8; ++e) v[e] = tmp[gi * 8 + e];
      int g = kh * 4 + gi;
      *(u16x8*)(dst + ((g ^ (n & 7)) << 4)) = v;
    }
    return;
  }

  float* coef = (float*)ws;
#pragma unroll
  for (int i = 0; i < 16; ++i) lc[t + i * 256] = cond[t + i * 256];
  __syncthreads();
  const int bid2 = blockIdx.x - 64;
  const int col = bid2 * 16 + (t & 15);
  const int ks = t >> 4;
  const float* src; int ncol, cl;
  if (col < 256)       { src = dgm; ncol = 256;  cl = col; }
  else if (col < 512)  { src = dbt; ncol = 256;  cl = col - 256; }
  else if (col < 1536) { src = ugm; ncol = 1024; cl = col - 512; }
  else                 { src = ubt; ncol = 1024; cl = col - 1536; }
  float acc[8] = {};
  for (int k = ks * 32; k < ks * 32 + 32; ++k) {
    float g = src[(size_t)k * ncol + cl];
#pragma unroll
    for (int b = 0; b < 8; ++b) acc[b] = fmaf(lc[b * 512 + k], g, acc[b]);
  }
#pragma unroll
  for (int b = 0; b < 8; ++b) red[(ks * 16 + (t & 15)) * 8 + b] = acc[b];
  __syncthreads();
  if (t < 128) {
    int c = t >> 3, b = t & 7;
    float s = 0.f;
#pragma unroll
    for (int k2 = 0; k2 < 16; ++k2) s += red[(k2 * 16 + c) * 8 + b];
    int colg = bid2 * 16 + c;
    float* dst; int ncol2, cl2;
    if (colg < 256)       { dst = coef + DG_OFF; ncol2 = 256;  cl2 = colg; }
    else if (colg < 512)  { dst = coef + DB_OFF; ncol2 = 256;  cl2 = colg - 256; }
    else if (colg < 1536) { dst = coef + UG_OFF; ncol2 = 1024; cl2 = colg - 512; }
    else                  { dst = coef + UB_OFF; ncol2 = 1024; cl2 = colg - 1536; }
    dst[b * ncol2 + cl2] = s;
  }
}

// ---------- fused kernel, 2 blocks/CU ----------
// 512 blocks x 512 threads (8 waves, 1m x 8n). BM=64 rows. LDS 80 KiB:
// act[4 kc][64 r][64 k]bf16 @0 (32K) | X f32 dbuf @32K (2x8K) | W dbuf @48K (2x16K)
__global__ __launch_bounds__(512, 4)
void fused_kernel(const float* __restrict__ X, char* __restrict__ ws,
                  float* __restrict__ out) {
  __shared__ char lds[81920];
  const int tid = threadIdx.x;
  const int lane = tid & 63;
  const int lr = lane & 15, lq = lane >> 4;
  const int wn = tid >> 6;          // wave index = n-split 0..7

  const int raw = blockIdx.x;
  const int m = (raw & 7) * 64 + (raw >> 3);   // XCD-chunked, 512 % 8 == 0
  const int row0 = m << 6;
  const int b = m >> 6;

  const float* coef = (const float*)ws;
  const char* w1 = ws + W1_BYTE;
  const char* w2 = ws + W2_BYTE;

  // ===== phase 1: X @ Wd  (BK=32, 32 steps) =====
  const int srow = tid >> 3, sg = tid & 7;
  const float* xsrc = X + (size_t)(row0 + srow) * 1024 + ((sg ^ (srow & 7)) << 2);

  int aoff[4][2], boff[2];
#pragma unroll
  for (int mf = 0; mf < 4; ++mf) {
    int r = mf * 16 + lr;
    aoff[mf][0] = r * 128 + (((2 * lq) ^ (r & 7)) << 4);
    aoff[mf][1] = r * 128 + (((2 * lq + 1) ^ (r & 7)) << 4);
  }
#pragma unroll
  for (int nf = 0; nf < 2; ++nf) {
    int n = wn * 32 + nf * 16 + lr;
    int R = n >> 1, G = (n & 1) * 4 + lq;
    boff[nf] = R * 128 + ((G ^ (R & 7)) << 4);
  }

  f32x4 acc1[4][2] = {};
  float hacc[4] = {};

#define STAGE_X(t)                                                               \
  gl_lds16(xsrc + (size_t)(t) * 32, lds + 32768 + ((t) & 1) * 8192 + tid * 16);
#define STAGE_W1(t)                                                              \
  { _Pragma("unroll")                                                            \
    for (int i = 0; i < 2; ++i)                                                  \
      gl_lds16(w1 + (size_t)(t) * 16384 + i * 8192 + tid * 16,                   \
               lds + 49152 + ((t) & 1) * 16384 + i * 8192 + tid * 16); }

  STAGE_X(0); STAGE_W1(0);
  STAGE_X(1); STAGE_W1(1);
  asm volatile("s_waitcnt vmcnt(3)" ::: "memory");
  __builtin_amdgcn_sched_barrier(0);
  __builtin_amdgcn_s_barrier();
  __builtin_amdgcn_sched_barrier(0);

  for (int t = 0; t < 32; ++t) {
    const char* Xc = lds + 32768 + (t & 1) * 8192;
    const char* Wc = lds + 49152 + (t & 1) * 16384;
    s16x8 afr[4];
#pragma unroll
    for (int mf = 0; mf < 4; ++mf) {
      f32x4 fa0 = *(const f32x4*)(Xc + aoff[mf][0]);
      f32x4 fa1 = *(const f32x4*)(Xc + aoff[mf][1]);
      if (wn == 0)
        hacc[mf] += fa0[0] + fa0[1] + fa0[2] + fa0[3] + fa1[0] + fa1[1] + fa1[2] + fa1[3];
      union { unsigned int u[4]; s16x8 s; } cv;
      cv.u[0] = cvt_pk(fa0[0], fa0[1]); cv.u[1] = cvt_pk(fa0[2], fa0[3]);
      cv.u[2] = cvt_pk(fa1[0], fa1[1]); cv.u[3] = cvt_pk(fa1[2], fa1[3]);
      afr[mf] = cv.s;
    }
    s16x8 bfr[2];
#pragma unroll
    for (int nf = 0; nf < 2; ++nf) bfr[nf] = *(const s16x8*)(Wc + boff[nf]);
#pragma unroll
    for (int mf = 0; mf < 4; ++mf)
#pragma unroll
      for (int nf = 0; nf < 2; ++nf)
        acc1[mf][nf] = __builtin_amdgcn_mfma_f32_16x16x32_bf16(afr[mf], bfr[nf], acc1[mf][nf], 0, 0, 0);

    asm volatile("s_waitcnt lgkmcnt(0)" ::: "memory");
    __builtin_amdgcn_sched_barrier(0);
    __builtin_amdgcn_s_barrier();
    __builtin_amdgcn_sched_barrier(0);
    if (t + 2 < 32) { STAGE_X(t + 2); STAGE_W1(t + 2); }
    if (t < 31) {
      if (t + 2 < 32) asm volatile("s_waitcnt vmcnt(3)" ::: "memory");
      else            asm volatile("s_waitcnt vmcnt(0)" ::: "memory");
      __builtin_amdgcn_sched_barrier(0);
      __builtin_amdgcn_s_barrier();
      __builtin_amdgcn_sched_barrier(0);
    }
  }

  // ===== phase-1 epilogue =====
  float* hsumb = (float*)(lds + 32768);          // 64 f32
  float* asp   = (float*)(lds + 33024);          // [8][64] f32
#pragma unroll
  for (int mf = 0; mf < 4; ++mf) {
    float s = hacc[mf];
    s += __shfl_xor(s, 16); s += __shfl_xor(s, 32);
    if (wn == 0 && lq == 0) hsumb[mf * 16 + lr] = s;
  }
  __syncthreads();

  float dgv[2], dbv[2];
#pragma unroll
  for (int nf = 0; nf < 2; ++nf) {
    int h = wn * 32 + nf * 16 + lr;
    dgv[nf] = coef[DG_OFF + b * 256 + h];
    dbv[nf] = coef[DB_OFF + b * 256 + h];
  }

  float asacc[4][4] = {};
  {
    char* kcb = lds + (wn >> 1) * 8192 + (lr & 7) * 2;
#pragma unroll
    for (int nf = 0; nf < 2; ++nf) {
      int g = (wn & 1) * 4 + nf * 2 + (lr >> 3);
      float dg_ = dgv[nf], db_ = dbv[nf];
#pragma unroll
      for (int mf = 0; mf < 4; ++mf) {
        int rb = mf * 16 + lq * 4;
#pragma unroll
        for (int j = 0; j < 4; ++j) {
          int r = rb + j;
          float v = acc1[mf][nf][j] * dg_ + db_ * hsumb[r];
          v = fmaxf(v, 0.f);
          asacc[mf][j] += v;
          *(unsigned short*)(kcb + r * 128 + ((g ^ (r & 7)) << 4)) = f2bf(v);
        }
      }
    }
  }
#pragma unroll
  for (int mf = 0; mf < 4; ++mf)
#pragma unroll
    for (int j = 0; j < 4; ++j) {
      float s = asacc[mf][j];
      s += __shfl_xor(s, 1); s += __shfl_xor(s, 2); s += __shfl_xor(s, 4); s += __shfl_xor(s, 8);
      if (lr == 0) asp[wn * 64 + mf * 16 + lq * 4 + j] = s;
    }
  __syncthreads();

  // ===== phase-2 preloads =====
  float asv[4][4];
#pragma unroll
  for (int mf = 0; mf < 4; ++mf)
#pragma unroll
    for (int j = 0; j < 4; ++j) {
      int r = mf * 16 + lq * 4 + j;
      float s = 0.f;
#pragma unroll
      for (int w = 0; w < 8; ++w) s += asp[w * 64 + r];
      asv[mf][j] = s;
    }
  float ugA[8], ubA[8];
#pragma unroll
  for (int nt = 0; nt < 8; ++nt) {
    int d = nt * 128 + wn * 16 + lr;
    ugA[nt] = coef[UG_OFF + b * 1024 + d];
    ubA[nt] = coef[UB_OFF + b * 1024 + d];
  }

  int a2off[4][2], b2off[2];
#pragma unroll
  for (int mf = 0; mf < 4; ++mf)
#pragma unroll
    for (int kf = 0; kf < 2; ++kf) {
      int r = mf * 16 + lr;
      a2off[mf][kf] = r * 128 + (((kf * 4 + lq) ^ (r & 7)) << 4);
    }
#pragma unroll
  for (int kf = 0; kf < 2; ++kf) {
    int nl = wn * 16 + lr;
    b2off[kf] = nl * 128 + (((kf * 4 + lq) ^ (nl & 7)) << 4);
  }

#define STAGE_W2(s)                                                              \
  { _Pragma("unroll")                                                            \
    for (int i = 0; i < 2; ++i)                                                  \
      gl_lds16(w2 + (size_t)(s) * 16384 + i * 8192 + tid * 16,                   \
               lds + 49152 + ((s) & 1) * 16384 + i * 8192 + tid * 16); }

  __builtin_amdgcn_sched_barrier(0);
  STAGE_W2(0); STAGE_W2(1);
  asm volatile("s_waitcnt vmcnt(2)" ::: "memory");
  __builtin_amdgcn_sched_barrier(0);
  __builtin_amdgcn_s_barrier();
  __builtin_amdgcn_sched_barrier(0);

  // ===== phase 2: act @ Wu, nt unrolled (ug/ub static-indexed) =====
#pragma unroll
  for (int nt = 0; nt < 8; ++nt) {
    f32x4 acc2[4] = {};
#pragma unroll
    for (int kc = 0; kc < 4; ++kc) {
      const int s = nt * 4 + kc;
      const char* Ac = lds + kc * 8192;
      const char* Wc2 = lds + 49152 + (kc & 1) * 16384;
#pragma unroll
      for (int kf = 0; kf < 2; ++kf) {
        s16x8 a2[4], bb;
#pragma unroll
        for (int mf = 0; mf < 4; ++mf) a2[mf] = *(const s16x8*)(Ac + a2off[mf][kf]);
        bb = *(const s16x8*)(Wc2 + b2off[kf]);
#pragma unroll
        for (int mf = 0; mf < 4; ++mf)
          acc2[mf] = __builtin_amdgcn_mfma_f32_16x16x32_bf16(a2[mf], bb, acc2[mf], 0, 0, 0);
      }
      asm volatile("s_waitcnt lgkmcnt(0)" ::: "memory");
      __builtin_amdgcn_sched_barrier(0);
      __builtin_amdgcn_s_barrier();
      __builtin_amdgcn_sched_barrier(0);

      if (s + 2 < 32) STAGE_W2(s + 2);
      if (kc == 3) {
        // epilogue for nt: 16 X loads + 16 stores (counted in vmcnt below)
#pragma unroll
        for (int mf = 0; mf < 4; ++mf)
#pragma unroll
          for (int j = 0; j < 4; ++j) {
            int r = mf * 16 + lq * 4 + j;
            size_t gi = (size_t)(row0 + r) * 1024 + nt * 128 + wn * 16 + lr;
            out[gi] = acc2[mf][j] * ugA[nt] + ubA[nt] * asv[mf][j] + X[gi];
          }
      }
      if (s < 31) {
        if (kc == 3)          asm volatile("s_waitcnt vmcnt(34)" ::: "memory");
        else if (s + 2 < 32)  asm volatile("s_waitcnt vmcnt(2)"  ::: "memory");
        else                  asm volatile("s_waitcnt vmcnt(0)"  ::: "memory");
        __builtin_amdgcn_sched_barrier(0);
        __builtin_amdgcn_s_barrier();
        __builtin_amdgcn_sched_barrier(0);
      }
    }
  }
}

extern "C" void kernel_launch(void* const* d_in, const int* in_sizes, int n_in,
                              void* d_out, int out_size, void* d_ws, size_t ws_size,
                              hipStream_t stream) {
  const float* hidden       = (const float*)d_in[0];
  const float* conditions   = (const float*)d_in[1];
  const float* down_project = (const float*)d_in[2];
  const float* down_gamma   = (const float*)d_in[3];
  const float* down_beta    = (const float*)d_in[4];
  const float* up_project   = (const float*)d_in[5];
  const float* up_gamma     = (const float*)d_in[6];
  const float* up_beta      = (const float*)d_in[7];
  float* out = (float*)d_out;
  char* ws = (char*)d_ws;

  prep_kernel<<<224, 256, 0, stream>>>(conditions, down_gamma, down_beta, up_gamma, up_beta,
                                       down_project, up_project, ws);
  fused_kernel<<<512, 512, 0, stream>>>(hidden, ws, out);
}